// Round 7
// baseline (4445.344 us; speedup 1.0000x reference)
//
#include <hip/hip_runtime.h>
#include <cstdint>
#include <cstddef>

#define TLEN 500
#define BATCH 128
#define NDIM 300
#define EDIM 128
#define CDIM 128
#define UDIM 64
#define FDIM 4
#define G3 384           // 3*E == 3*C
#define CLIPV 5.0f
#define NL 192           // Whh rows resident in LDS (wave-aligned: waves 0-2)

// ---------------------------------------------------------------------------
// R12. Evidence: R11's 64-block ctrl (2 batches/blk) REGRESSED 871->1152 us
// (Occupancy 4.5%, VALUBusy 15.8%): fewer CUs + doubled per-block serial work
// kills latency hiding. Register residency unobtainable (VGPR 88-120 across
// R7-R11). New lever: WEIGHTS IN LDS. Each scan block stages Whh rows 0..NL-1
// (96 KB) into LDS once (bank-swizzled: slot = k ^ (row&31) -> balanced
// permutation, full-rate ds_read_b128); waves 3-5 stream rows NL..383 from L2
// (L2-resident, ~98 KB/step/blk; per-XCD demand under ceiling). h broadcast
// stays readlane (k-order uniform; swizzle permutes STORAGE only).
// ctrl grid back to 128 blocks (1 batch/blk). Decoder stays externalized (R6,
// verified absmax 0.25).
// ---------------------------------------------------------------------------
#define REP32(M) M(0) M(1) M(2) M(3) M(4) M(5) M(6) M(7) \
                 M(8) M(9) M(10) M(11) M(12) M(13) M(14) M(15) \
                 M(16) M(17) M(18) M(19) M(20) M(21) M(22) M(23) \
                 M(24) M(25) M(26) M(27) M(28) M(29) M(30) M(31)

// broadcast h element j (0..127) from lane registers h0/h1 (readlane needs all
// 64 lanes of the wave live -> only call from wave-uniform control flow)
#define RLH(j) __int_as_float(__builtin_amdgcn_readlane(((j) < 64) ? h0 : h1, (j) & 63))
#define DOTL(k) { const float4 wv = wrow[(k) ^ sw]; \
                  a0 = fmaf(wv.x, RLH(4*(k)+0), a0); \
                  a1 = fmaf(wv.y, RLH(4*(k)+1), a1); \
                  a2 = fmaf(wv.z, RLH(4*(k)+2), a2); \
                  a3 = fmaf(wv.w, RLH(4*(k)+3), a3); }
#define DOTG(k) { const float4 wv = gsrc[(k)]; \
                  a0 = fmaf(wv.x, RLH(4*(k)+0), a0); \
                  a1 = fmaf(wv.y, RLH(4*(k)+1), a1); \
                  a2 = fmaf(wv.z, RLH(4*(k)+2), a2); \
                  a3 = fmaf(wv.w, RLH(4*(k)+3), a3); }

static __device__ __forceinline__ float sigm(float x) {
    return 1.0f / (1.0f + expf(-x));
}

// ---------------------------------------------------------------------------
// Fused GEMM (UNCHANGED from R11, verified): C = bias + A1@W[:,wofs1:]^T
// (+ A2@W[:,wofs2:]^T). 128x128 tile, BK=8, double-buffered LDS, 1 barrier
// per k-tile, bijective XCD swizzle, N-bounded float4 epilogue.
// ---------------------------------------------------------------------------
__global__ __launch_bounds__(256) void gemm_fused_kernel(
    const float* __restrict__ A1, int lda1, int K1, int wofs1,
    const float* __restrict__ A2, int lda2, int K2, int wofs2,
    const float* __restrict__ Wf, const float* __restrict__ biasf,
    float* __restrict__ Cf,
    const float* __restrict__ Wb, const float* __restrict__ biasb,
    float* __restrict__ Cb,
    int ldw, int ldc, int ndir, int ntpd, int Nmax)
{
    __shared__ float As[2][8][128];
    __shared__ float Bs[2][8][128];
    const int tid = threadIdx.x;

    const int npb = ntpd * ndir;
    const int nwg = 500 * npb;
    const int d   = blockIdx.x;
    const int xcd = d & 7, blk = d >> 3;
    const int q = nwg >> 3, r = nwg & 7;
    const int work = (xcd < r ? xcd * (q + 1) : r * (q + 1) + (xcd - r) * q) + blk;
    const int panel = work / npb;
    const int sub   = work - panel * npb;
    const int dir   = (sub >= ntpd) ? 1 : 0;
    const int nt    = sub - dir * ntpd;
    const int m0 = panel * 128;
    const int n0 = nt * 128;
    const float* __restrict__ W    = dir ? Wb : Wf;
    const float* __restrict__ bias = dir ? biasb : biasf;
    float* __restrict__ C          = dir ? Cb : Cf;

    const int lr = tid >> 1;
    const int lc = (tid & 1) << 2;
    const int ty = tid >> 4;
    const int tx = tid & 15;
    const int wrow = min(n0 + lr, Nmax - 1);

    float acc[8][8];
#pragma unroll
    for (int i = 0; i < 8; ++i)
#pragma unroll
        for (int j = 0; j < 8; ++j) acc[i][j] = 0.f;

    int buf = 0;
#pragma unroll 1
    for (int phase = 0; phase < 2; ++phase) {
        const float* __restrict__ A = phase ? A2 : A1;
        if (A == nullptr) continue;
        const int lda  = phase ? lda2  : lda1;
        const int K    = phase ? K2    : K1;
        const int wofs = phase ? wofs2 : wofs1;
        const float* __restrict__ Arow = A + (size_t)(m0 + lr) * lda;
        const float* __restrict__ Wrow = W + (size_t)wrow * ldw + wofs;

        {
            float4 av = make_float4(0.f, 0.f, 0.f, 0.f);
            float4 bv = make_float4(0.f, 0.f, 0.f, 0.f);
            if (lc < K) {
                av = *(const float4*)(Arow + lc);
                bv = *(const float4*)(Wrow + lc);
            }
            As[buf][lc + 0][lr] = av.x; As[buf][lc + 1][lr] = av.y;
            As[buf][lc + 2][lr] = av.z; As[buf][lc + 3][lr] = av.w;
            Bs[buf][lc + 0][lr] = bv.x; Bs[buf][lc + 1][lr] = bv.y;
            Bs[buf][lc + 2][lr] = bv.z; Bs[buf][lc + 3][lr] = bv.w;
            __syncthreads();
        }
#pragma unroll 1
        for (int k0 = 0; k0 < K; k0 += 8) {
            const bool more = (k0 + 8 < K);
            float4 av = make_float4(0.f, 0.f, 0.f, 0.f);
            float4 bv = make_float4(0.f, 0.f, 0.f, 0.f);
            if (more) {
                const int kn = k0 + 8 + lc;
                if (kn < K) {
                    av = *(const float4*)(Arow + kn);
                    bv = *(const float4*)(Wrow + kn);
                }
            }
            const float (*__restrict__ Asb)[128] = As[buf];
            const float (*__restrict__ Bsb)[128] = Bs[buf];
#pragma unroll
            for (int kk = 0; kk < 8; ++kk) {
                float a[8], bb[8];
#pragma unroll
                for (int i = 0; i < 4; ++i) {
                    a[i]     = Asb[kk][ty * 4 + i];
                    a[4 + i] = Asb[kk][64 + ty * 4 + i];
                }
#pragma unroll
                for (int j = 0; j < 4; ++j) {
                    bb[j]     = Bsb[kk][tx * 4 + j];
                    bb[4 + j] = Bsb[kk][64 + tx * 4 + j];
                }
#pragma unroll
                for (int i = 0; i < 8; ++i)
#pragma unroll
                    for (int j = 0; j < 8; ++j)
                        acc[i][j] = fmaf(a[i], bb[j], acc[i][j]);
            }
            if (more) {
                float (*__restrict__ Asn)[128] = As[buf ^ 1];
                float (*__restrict__ Bsn)[128] = Bs[buf ^ 1];
                Asn[lc + 0][lr] = av.x; Asn[lc + 1][lr] = av.y;
                Asn[lc + 2][lr] = av.z; Asn[lc + 3][lr] = av.w;
                Bsn[lc + 0][lr] = bv.x; Bsn[lc + 1][lr] = bv.y;
                Bsn[lc + 2][lr] = bv.z; Bsn[lc + 3][lr] = bv.w;
            }
            __syncthreads();
            buf ^= (int)more;
        }
    }
    const int cclo = n0 + tx * 4;
    const int cchi = n0 + 64 + tx * 4;
    const float4 bias_lo = *(const float4*)(bias + min(cclo, Nmax - 4));
    const float4 bias_hi = *(const float4*)(bias + min(cchi, Nmax - 4));
#pragma unroll
    for (int i = 0; i < 8; ++i) {
        const int rr = m0 + ((i < 4) ? (ty * 4 + i) : (64 + ty * 4 + (i - 4)));
        if (cclo < Nmax) {
            float4 lo = make_float4(acc[i][0] + bias_lo.x, acc[i][1] + bias_lo.y,
                                    acc[i][2] + bias_lo.z, acc[i][3] + bias_lo.w);
            *(float4*)(C + (size_t)rr * ldc + cclo) = lo;
        }
        if (cchi < Nmax) {
            float4 hi = make_float4(acc[i][4] + bias_hi.x, acc[i][5] + bias_hi.y,
                                    acc[i][6] + bias_hi.z, acc[i][7] + bias_hi.w);
            *(float4*)(C + (size_t)rr * ldc + cchi) = hi;
        }
    }
}

// ---------------------------------------------------------------------------
// R12 encoder GRU scans: 256 WGs (dir*128+b), 384 threads. Whh rows 0..NL-1
// staged into LDS (swizzled slot k^(row&31)); waves 3-5 stream rows NL..383
// from L2 in-loop. 2 barriers/step. LDS total ~100 KB.
// ---------------------------------------------------------------------------
__global__ __launch_bounds__(384) void enc_scan_kernel(
    const float* __restrict__ xp,
    const float* __restrict__ Whh_f, const float* __restrict__ bhh_f,
    const float* __restrict__ Whh_b, const float* __restrict__ bhh_b,
    const float* __restrict__ enc_init,
    float* __restrict__ g)
{
    const int wg  = blockIdx.x;
    const int dir = wg >> 7;
    const int b   = wg & 127;
    const int tid = threadIdx.x;
    const int lane = tid & 63;
    const float* __restrict__ Whh = dir ? Whh_b : Whh_f;
    const float* __restrict__ bhh = dir ? bhh_b : bhh_f;
    const float* __restrict__ xpd = xp + (size_t)dir * ((size_t)TLEN * BATCH * G3);

    __shared__ float4 wlds[NL * 32];   // 96 KB, swizzled
    __shared__ float h_lds[EDIM];
    __shared__ float hh_lds[G3];

    // one-time stage of rows 0..NL-1 (bank-swizzled)
    if (tid < NL) {
        const float4* src = (const float4*)(Whh + (size_t)tid * 128);
#pragma unroll
        for (int k = 0; k < 32; ++k)
            wlds[tid * 32 + (k ^ (tid & 31))] = src[k];
    }
    const float brow = bhh[tid];
    const float4* gsrc = (const float4*)(Whh + (size_t)tid * 128);  // waves 3-5
    if (tid < EDIM) h_lds[tid] = enc_init[dir * EDIM + tid];
    __syncthreads();

    for (int s = 0; s < TLEN; ++s) {
        const int t = dir ? (TLEN - 1 - s) : s;
        const size_t row = (size_t)t * BATCH + b;
        float xr = 0.f, xz = 0.f, xn = 0.f;
        if (tid < EDIM) {
            const float* __restrict__ xrow = xpd + row * G3;
            xr = xrow[tid]; xz = xrow[EDIM + tid]; xn = xrow[2 * EDIM + tid];
        }
        const int h0 = __float_as_int(h_lds[lane]);
        const int h1 = __float_as_int(h_lds[64 + lane]);
        float a0 = 0.f, a1 = 0.f, a2 = 0.f, a3 = 0.f;
        if (tid < NL) {                       // waves 0-2: LDS-resident weights
            const float4* __restrict__ wrow = &wlds[tid * 32];
            const int sw = tid & 31;
            REP32(DOTL)
        } else {                              // waves 3-5: L2-streamed weights
            REP32(DOTG)
        }
        hh_lds[tid] = ((a0 + a1) + (a2 + a3)) + brow;
        __syncthreads();  // A
        if (tid < EDIM) {
            const float hr = hh_lds[tid], hz = hh_lds[EDIM + tid], hn = hh_lds[2 * EDIM + tid];
            const float r = sigm(xr + hr);
            const float z = sigm(xz + hz);
            const float n = tanhf(xn + r * hn);
            const float hold = (tid < 64) ? __int_as_float(h0) : __int_as_float(h1);
            const float hnew = (1.f - z) * n + z * hold;   // carry UNclipped (ref)
            h_lds[tid] = hnew;
            g[row * (2 * EDIM) + dir * EDIM + tid] = fminf(fmaxf(hnew, -CLIPV), CLIPV);
        }
        __syncthreads();  // B
    }
}

// ---------------------------------------------------------------------------
// R12 ctrl GRU scan: GRU-only, 128 WGs (1 batch each) x 384 threads, same
// LDS-resident weight scheme. Writes clipped h_t to hseq (carry clipped, ref).
// ---------------------------------------------------------------------------
__global__ __launch_bounds__(384) void ctrl_scan_kernel(
    const float* __restrict__ cp,       // [T*B, 384]
    const float* __restrict__ Whh, const float* __restrict__ bhh,
    const float* __restrict__ ctrl_init,
    float* __restrict__ hseq)           // [T*B, 128]
{
    const int b    = blockIdx.x;
    const int tid  = threadIdx.x;
    const int lane = tid & 63;

    __shared__ float4 wlds[NL * 32];   // 96 KB, swizzled
    __shared__ float h_lds[CDIM];
    __shared__ float hh_lds[G3];

    if (tid < NL) {
        const float4* src = (const float4*)(Whh + (size_t)tid * 128);
#pragma unroll
        for (int k = 0; k < 32; ++k)
            wlds[tid * 32 + (k ^ (tid & 31))] = src[k];
    }
    const float brow = bhh[tid];
    const float4* gsrc = (const float4*)(Whh + (size_t)tid * 128);
    if (tid < CDIM) h_lds[tid] = ctrl_init[tid];
    __syncthreads();

    for (int t = 0; t < TLEN; ++t) {
        const size_t row = (size_t)t * BATCH + b;
        float cxr = 0.f, cxz = 0.f, cxn = 0.f;
        if (tid < CDIM) {
            const float* __restrict__ cpr = cp + row * G3;
            cxr = cpr[tid]; cxz = cpr[CDIM + tid]; cxn = cpr[2 * CDIM + tid];
        }
        const int h0 = __float_as_int(h_lds[lane]);
        const int h1 = __float_as_int(h_lds[64 + lane]);
        float a0 = 0.f, a1 = 0.f, a2 = 0.f, a3 = 0.f;
        if (tid < NL) {
            const float4* __restrict__ wrow = &wlds[tid * 32];
            const int sw = tid & 31;
            REP32(DOTL)
        } else {
            REP32(DOTG)
        }
        hh_lds[tid] = ((a0 + a1) + (a2 + a3)) + brow;
        __syncthreads();  // A
        if (tid < CDIM) {
            const float hr = hh_lds[tid], hz = hh_lds[CDIM + tid], hn = hh_lds[2 * CDIM + tid];
            const float r = sigm(cxr + hr);
            const float z = sigm(cxz + hz);
            const float n = tanhf(cxn + r * hn);
            const float hold = (tid < 64) ? __int_as_float(h0) : __int_as_float(h1);
            float hnew = (1.f - z) * n + z * hold;
            hnew = fminf(fmaxf(hnew, -CLIPV), CLIPV);      // carry clipped (ref)
            h_lds[tid] = hnew;
            hseq[row * CDIM + tid] = hnew;
        }
        __syncthreads();  // B
    }
}

// ---------------------------------------------------------------------------
// Concat [W_mu; W_lv] -> dst[128][128], [b_mu; b_lv] -> dst+16384. One block.
// ---------------------------------------------------------------------------
__global__ __launch_bounds__(256) void prep_mulv_kernel(
    const float* __restrict__ W_mu, const float* __restrict__ b_mu,
    const float* __restrict__ W_lv, const float* __restrict__ b_lv,
    float* __restrict__ dst)
{
    const int tid = threadIdx.x;
    for (int i = tid; i < UDIM * CDIM; i += 256) {
        dst[i] = W_mu[i];
        dst[UDIM * CDIM + i] = W_lv[i];
    }
    if (tid < UDIM) {
        dst[2 * UDIM * CDIM + tid] = b_mu[tid];
        dst[2 * UDIM * CDIM + UDIM + tid] = b_lv[tid];
    }
}

// ---------------------------------------------------------------------------
// u/gen: gen[row][0:64] = mu + exp(0.5 lv)*eps ; gen[row][64:68] = factors.
// ---------------------------------------------------------------------------
__global__ __launch_bounds__(128) void ugen_kernel(
    const float* __restrict__ mulv,     // [64000, 128] (mu | lv)
    const float* __restrict__ eps,      // [64000, 64]
    const float* __restrict__ factors,  // [64000, 4]
    float* __restrict__ gen)            // [64000, 68]
{
    const size_t row = blockIdx.x;
    const int tid = threadIdx.x;
    if (tid < UDIM) {
        const float mu = mulv[row * 128 + tid];
        const float lv = mulv[row * 128 + UDIM + tid];
        gen[row * (UDIM + FDIM) + tid] = mu + expf(0.5f * lv) * eps[row * UDIM + tid];
    } else if (tid < UDIM + FDIM) {
        gen[row * (UDIM + FDIM) + tid] = factors[row * FDIM + (tid - UDIM)];
    }
}

// ---------------------------------------------------------------------------
// AR1 calcium over t: 38400 independent (b,n) chains, coalesced per t.
// ---------------------------------------------------------------------------
__global__ __launch_bounds__(256) void ar1_kernel(
    const float* __restrict__ spike,    // [T*B, 300] raw gen@Wspk.T + b_spk
    const float* __restrict__ gain_p, const float* __restrict__ bias_p_p,
    const float* __restrict__ logtau_p,
    float* __restrict__ out)            // [T, B, 300]
{
    const int id = blockIdx.x * 256 + threadIdx.x;
    if (id >= BATCH * NDIM) return;
    const float gain  = gain_p[0];
    const float biasp = bias_p_p[0];
    const float decay = 1.0f - expf(-logtau_p[0]);
    float cal = 0.f;
#pragma unroll 4
    for (int t = 0; t < TLEN; ++t) {
        const float v  = spike[(size_t)t * (BATCH * NDIM) + id];
        const float sp = fmaxf(expf(v) - 1.0f, 0.0f);
        cal = cal * decay + gain * sp + biasp;
        out[(size_t)t * (BATCH * NDIM) + id] = cal;
    }
}

// ---------------------------------------------------------------------------
extern "C" void kernel_launch(void* const* d_in, const int* in_sizes, int n_in,
                              void* d_out, int out_size, void* d_ws, size_t ws_size,
                              hipStream_t stream) {
    const float* x         = (const float*)d_in[0];
    const float* factors   = (const float*)d_in[1];
    const float* eps       = (const float*)d_in[2];
    const float* enc_Wih_f = (const float*)d_in[3];
    const float* enc_Whh_f = (const float*)d_in[4];
    const float* enc_bih_f = (const float*)d_in[5];
    const float* enc_bhh_f = (const float*)d_in[6];
    const float* enc_Wih_b = (const float*)d_in[7];
    const float* enc_Whh_b = (const float*)d_in[8];
    const float* enc_bih_b = (const float*)d_in[9];
    const float* enc_bhh_b = (const float*)d_in[10];
    const float* enc_init  = (const float*)d_in[11];
    const float* ctrl_Wih  = (const float*)d_in[12];
    const float* ctrl_Whh  = (const float*)d_in[13];
    const float* ctrl_bih  = (const float*)d_in[14];
    const float* ctrl_bhh  = (const float*)d_in[15];
    const float* ctrl_init = (const float*)d_in[16];
    const float* W_mu      = (const float*)d_in[17];
    const float* b_mu      = (const float*)d_in[18];
    const float* W_lv      = (const float*)d_in[19];
    const float* b_lv      = (const float*)d_in[20];
    const float* W_spk     = (const float*)d_in[21];
    const float* b_spk     = (const float*)d_in[22];
    const float* gain      = (const float*)d_in[23];
    const float* bias_p    = (const float*)d_in[24];
    const float* logtau    = (const float*)d_in[25];
    float* out = (float*)d_out;
    float* ws  = (float*)d_ws;

    const size_t PROJ = (size_t)TLEN * BATCH * G3;   // 24,576,000 floats
    const size_t ROWS = (size_t)TLEN * BATCH;        // 64,000
    float* xpf   = ws;                     // [T*B,384]  -> later cp -> later spike
    float* xpb   = ws + PROJ;              // [T*B,384]  -> later hseq/mulv/gen
    float* g     = ws + 2 * PROJ;          // [T*B,256]  -> later wsmulv
    float* cp    = xpf;
    float* hseq  = xpb;                    // [T*B,128]
    float* mulv  = xpb + ROWS * 128;       // [T*B,128]
    float* gen   = xpb + 2 * ROWS * 128;   // [T*B,68]
    float* spike = xpf;                    // [T*B,300]
    float* wsmulv = g;                     // 16512 floats

    // 1) merged encoder projections
    gemm_fused_kernel<<<3000, 256, 0, stream>>>(
        x, NDIM, NDIM, 0,
        nullptr, 0, 0, 0,
        enc_Wih_f, enc_bih_f, xpf,
        enc_Wih_b, enc_bih_b, xpb,
        NDIM, G3, 2, 3, G3);
    // 2) bidirectional encoder scans -> g (clipped)
    enc_scan_kernel<<<256, 384, 0, stream>>>(xpf, enc_Whh_f, enc_bhh_f,
                                             enc_Whh_b, enc_bhh_b, enc_init, g);
    // 3) cp = g @ ctrl_Wih[:, :256].T + x @ ctrl_Wih[:, 256:].T + ctrl_bih
    gemm_fused_kernel<<<1500, 256, 0, stream>>>(
        g, 2 * EDIM, 2 * EDIM, 0,
        x, NDIM, NDIM, 2 * EDIM,
        ctrl_Wih, ctrl_bih, cp,
        nullptr, nullptr, nullptr,
        2 * EDIM + NDIM, G3, 1, 3, G3);
    // 4) concat W_mu/W_lv
    prep_mulv_kernel<<<1, 256, 0, stream>>>(W_mu, b_mu, W_lv, b_lv, wsmulv);
    // 5) controller GRU scan -> hseq (clipped)
    ctrl_scan_kernel<<<128, 384, 0, stream>>>(cp, ctrl_Whh, ctrl_bhh, ctrl_init, hseq);
    // 6) mulv = hseq @ [W_mu;W_lv].T + [b_mu;b_lv]
    gemm_fused_kernel<<<500, 256, 0, stream>>>(
        hseq, CDIM, CDIM, 0,
        nullptr, 0, 0, 0,
        wsmulv, wsmulv + 2 * UDIM * CDIM, mulv,
        nullptr, nullptr, nullptr,
        CDIM, CDIM, 1, 1, CDIM);
    // 7) gen = [mu + exp(0.5 lv)*eps | factors]
    ugen_kernel<<<(int)ROWS, 128, 0, stream>>>(mulv, eps, factors, gen);
    // 8) spike_raw = gen @ W_spk.T + b_spk
    gemm_fused_kernel<<<1500, 256, 0, stream>>>(
        gen, UDIM + FDIM, UDIM + FDIM, 0,
        nullptr, 0, 0, 0,
        W_spk, b_spk, spike,
        nullptr, nullptr, nullptr,
        UDIM + FDIM, NDIM, 1, 3, NDIM);
    // 9) calcium AR1 -> out
    ar1_kernel<<<(BATCH * NDIM + 255) / 256, 256, 0, stream>>>(
        spike, gain, bias_p, logtau, out);
}

// Round 8
// 2024.294 us; speedup vs baseline: 2.1960x; 2.1960x over previous
//
#include <hip/hip_runtime.h>
#include <cstdint>
#include <cstddef>

#define TLEN 500
#define BATCH 128
#define NDIM 300
#define EDIM 128
#define CDIM 128
#define UDIM 64
#define FDIM 4
#define G3 384           // 3*E == 3*C
#define CLIPV 5.0f

// ---------------------------------------------------------------------------
// R13. R12's LDS-resident weights REGRESSED 2.2x (enc 1794 us, 1 blk/CU,
// VALUBusy 17%, conflicts 0): ds_read->FMA chains at ~120cyc latency with only
// 6 waves/CU don't pipeline; L2 streaming DOES (deep vmcnt queues). Evidence
// across R5/R11/R12: scans are bound by weight-load CONCURRENCY, not bytes
// alone (R5 ctrl: 8 waves = 87 B/cyc/CU; 6-wave enc ~50 B/cyc). R13: SPLIT-K
// streaming scans -- 768 threads (12 waves), thread r<384 does k=0..63 of row
// r, thread 384+r does k=64..127; partials combined via 3KB LDS. Same bytes,
// 2x loads in flight, half the serial FMA+readlane chain per thread. Gates
// biases hoisted (loop-invariant). ctrl = GRU-only 128 blocks; decoder stays
// externalized (verified R11/R12, absmax 0.25).
// ---------------------------------------------------------------------------
#define REP16(M) M(0) M(1) M(2) M(3) M(4) M(5) M(6) M(7) \
                 M(8) M(9) M(10) M(11) M(12) M(13) M(14) M(15)

// broadcast h element j (0..63) from lane register hreg (readlane needs all
// 64 lanes of the wave live -> dot executed unconditionally by all threads)
#define RLX(j) __int_as_float(__builtin_amdgcn_readlane(hreg, (j)))
#define DOTH(i) { const float4 wv = wsrc[i]; \
                  a0 = fmaf(wv.x, RLX(4*(i)+0), a0); \
                  a1 = fmaf(wv.y, RLX(4*(i)+1), a1); \
                  a2 = fmaf(wv.z, RLX(4*(i)+2), a2); \
                  a3 = fmaf(wv.w, RLX(4*(i)+3), a3); }

static __device__ __forceinline__ float sigm(float x) {
    return 1.0f / (1.0f + expf(-x));
}

// ---------------------------------------------------------------------------
// Fused GEMM (UNCHANGED, verified): C = bias + A1@W[:,wofs1:]^T
// (+ A2@W[:,wofs2:]^T). 128x128 tile, BK=8, double-buffered LDS, 1 barrier
// per k-tile, bijective XCD swizzle, N-bounded float4 epilogue.
// ---------------------------------------------------------------------------
__global__ __launch_bounds__(256) void gemm_fused_kernel(
    const float* __restrict__ A1, int lda1, int K1, int wofs1,
    const float* __restrict__ A2, int lda2, int K2, int wofs2,
    const float* __restrict__ Wf, const float* __restrict__ biasf,
    float* __restrict__ Cf,
    const float* __restrict__ Wb, const float* __restrict__ biasb,
    float* __restrict__ Cb,
    int ldw, int ldc, int ndir, int ntpd, int Nmax)
{
    __shared__ float As[2][8][128];
    __shared__ float Bs[2][8][128];
    const int tid = threadIdx.x;

    const int npb = ntpd * ndir;
    const int nwg = 500 * npb;
    const int d   = blockIdx.x;
    const int xcd = d & 7, blk = d >> 3;
    const int q = nwg >> 3, r = nwg & 7;
    const int work = (xcd < r ? xcd * (q + 1) : r * (q + 1) + (xcd - r) * q) + blk;
    const int panel = work / npb;
    const int sub   = work - panel * npb;
    const int dir   = (sub >= ntpd) ? 1 : 0;
    const int nt    = sub - dir * ntpd;
    const int m0 = panel * 128;
    const int n0 = nt * 128;
    const float* __restrict__ W    = dir ? Wb : Wf;
    const float* __restrict__ bias = dir ? biasb : biasf;
    float* __restrict__ C          = dir ? Cb : Cf;

    const int lr = tid >> 1;
    const int lc = (tid & 1) << 2;
    const int ty = tid >> 4;
    const int tx = tid & 15;
    const int wrow = min(n0 + lr, Nmax - 1);

    float acc[8][8];
#pragma unroll
    for (int i = 0; i < 8; ++i)
#pragma unroll
        for (int j = 0; j < 8; ++j) acc[i][j] = 0.f;

    int buf = 0;
#pragma unroll 1
    for (int phase = 0; phase < 2; ++phase) {
        const float* __restrict__ A = phase ? A2 : A1;
        if (A == nullptr) continue;
        const int lda  = phase ? lda2  : lda1;
        const int K    = phase ? K2    : K1;
        const int wofs = phase ? wofs2 : wofs1;
        const float* __restrict__ Arow = A + (size_t)(m0 + lr) * lda;
        const float* __restrict__ Wrow = W + (size_t)wrow * ldw + wofs;

        {
            float4 av = make_float4(0.f, 0.f, 0.f, 0.f);
            float4 bv = make_float4(0.f, 0.f, 0.f, 0.f);
            if (lc < K) {
                av = *(const float4*)(Arow + lc);
                bv = *(const float4*)(Wrow + lc);
            }
            As[buf][lc + 0][lr] = av.x; As[buf][lc + 1][lr] = av.y;
            As[buf][lc + 2][lr] = av.z; As[buf][lc + 3][lr] = av.w;
            Bs[buf][lc + 0][lr] = bv.x; Bs[buf][lc + 1][lr] = bv.y;
            Bs[buf][lc + 2][lr] = bv.z; Bs[buf][lc + 3][lr] = bv.w;
            __syncthreads();
        }
#pragma unroll 1
        for (int k0 = 0; k0 < K; k0 += 8) {
            const bool more = (k0 + 8 < K);
            float4 av = make_float4(0.f, 0.f, 0.f, 0.f);
            float4 bv = make_float4(0.f, 0.f, 0.f, 0.f);
            if (more) {
                const int kn = k0 + 8 + lc;
                if (kn < K) {
                    av = *(const float4*)(Arow + kn);
                    bv = *(const float4*)(Wrow + kn);
                }
            }
            const float (*__restrict__ Asb)[128] = As[buf];
            const float (*__restrict__ Bsb)[128] = Bs[buf];
#pragma unroll
            for (int kk = 0; kk < 8; ++kk) {
                float a[8], bb[8];
#pragma unroll
                for (int i = 0; i < 4; ++i) {
                    a[i]     = Asb[kk][ty * 4 + i];
                    a[4 + i] = Asb[kk][64 + ty * 4 + i];
                }
#pragma unroll
                for (int j = 0; j < 4; ++j) {
                    bb[j]     = Bsb[kk][tx * 4 + j];
                    bb[4 + j] = Bsb[kk][64 + tx * 4 + j];
                }
#pragma unroll
                for (int i = 0; i < 8; ++i)
#pragma unroll
                    for (int j = 0; j < 8; ++j)
                        acc[i][j] = fmaf(a[i], bb[j], acc[i][j]);
            }
            if (more) {
                float (*__restrict__ Asn)[128] = As[buf ^ 1];
                float (*__restrict__ Bsn)[128] = Bs[buf ^ 1];
                Asn[lc + 0][lr] = av.x; Asn[lc + 1][lr] = av.y;
                Asn[lc + 2][lr] = av.z; Asn[lc + 3][lr] = av.w;
                Bsn[lc + 0][lr] = bv.x; Bsn[lc + 1][lr] = bv.y;
                Bsn[lc + 2][lr] = bv.z; Bsn[lc + 3][lr] = bv.w;
            }
            __syncthreads();
            buf ^= (int)more;
        }
    }
    const int cclo = n0 + tx * 4;
    const int cchi = n0 + 64 + tx * 4;
    const float4 bias_lo = *(const float4*)(bias + min(cclo, Nmax - 4));
    const float4 bias_hi = *(const float4*)(bias + min(cchi, Nmax - 4));
#pragma unroll
    for (int i = 0; i < 8; ++i) {
        const int rr = m0 + ((i < 4) ? (ty * 4 + i) : (64 + ty * 4 + (i - 4)));
        if (cclo < Nmax) {
            float4 lo = make_float4(acc[i][0] + bias_lo.x, acc[i][1] + bias_lo.y,
                                    acc[i][2] + bias_lo.z, acc[i][3] + bias_lo.w);
            *(float4*)(C + (size_t)rr * ldc + cclo) = lo;
        }
        if (cchi < Nmax) {
            float4 hi = make_float4(acc[i][4] + bias_hi.x, acc[i][5] + bias_hi.y,
                                    acc[i][6] + bias_hi.z, acc[i][7] + bias_hi.w);
            *(float4*)(C + (size_t)rr * ldc + cchi) = hi;
        }
    }
}

// ---------------------------------------------------------------------------
// R13 encoder GRU scans: 256 WGs (dir*128+b), 768 threads (12 waves).
// Split-K: thread r<384 computes k=0..63 of Whh row r; thread 384+r computes
// k=64..127. Partials -> ph[768] (LDS, 3KB); gates thread j (<128) combines
// ph[row]+ph[384+row]+bias (biases hoisted). 2 barriers/step. Carry h is
// UNclipped (ref); g output clipped.
// ---------------------------------------------------------------------------
__global__ __launch_bounds__(768) void enc_scan_kernel(
    const float* __restrict__ xp,
    const float* __restrict__ Whh_f, const float* __restrict__ bhh_f,
    const float* __restrict__ Whh_b, const float* __restrict__ bhh_b,
    const float* __restrict__ enc_init,
    float* __restrict__ g)
{
    const int wg  = blockIdx.x;
    const int dir = wg >> 7;
    const int b   = wg & 127;
    const int tid = threadIdx.x;
    const int lane = tid & 63;
    const int half = (tid >= 384) ? 1 : 0;     // wave-uniform (wave 6 boundary)
    const int row  = tid - half * 384;
    const float* __restrict__ Whh = dir ? Whh_b : Whh_f;
    const float* __restrict__ bhh = dir ? bhh_b : bhh_f;
    const float* __restrict__ xpd = xp + (size_t)dir * ((size_t)TLEN * BATCH * G3);

    __shared__ float ph[768];          // split-K partials
    __shared__ float h_lds[EDIM];

    const float4* __restrict__ wsrc = (const float4*)(Whh + (size_t)row * 128 + half * 64);
    // gates-thread loop-invariant biases
    float br = 0.f, bz = 0.f, bn = 0.f;
    if (tid < EDIM) {
        br = bhh[tid]; bz = bhh[EDIM + tid]; bn = bhh[2 * EDIM + tid];
        h_lds[tid] = enc_init[dir * EDIM + tid];
    }
    __syncthreads();

    for (int s = 0; s < TLEN; ++s) {
        const int t = dir ? (TLEN - 1 - s) : s;
        const size_t row_g = (size_t)t * BATCH + b;
        // prefetch xp row + old h (consumed after barrier A)
        float xr = 0.f, xz = 0.f, xn = 0.f, hold = 0.f;
        if (tid < EDIM) {
            const float* __restrict__ xrow = xpd + row_g * G3;
            xr = xrow[tid]; xz = xrow[EDIM + tid]; xn = xrow[2 * EDIM + tid];
            hold = h_lds[tid];
        }
        // half-dot: 16 float4 loads, 64 readlane+fma (all 768 threads)
        const int hreg = __float_as_int(h_lds[half * 64 + lane]);
        float a0 = 0.f, a1 = 0.f, a2 = 0.f, a3 = 0.f;
        REP16(DOTH)
        ph[tid] = (a0 + a1) + (a2 + a3);
        __syncthreads();  // A
        if (tid < EDIM) {   // waves 0,1 fully active
            const float hr = ph[tid]            + ph[384 + tid]            + br;
            const float hz = ph[EDIM + tid]     + ph[384 + EDIM + tid]     + bz;
            const float hn = ph[2 * EDIM + tid] + ph[384 + 2 * EDIM + tid] + bn;
            const float rr = sigm(xr + hr);
            const float zz = sigm(xz + hz);
            const float nn = tanhf(xn + rr * hn);
            const float hnew = (1.f - zz) * nn + zz * hold;   // carry UNclipped
            h_lds[tid] = hnew;
            g[row_g * (2 * EDIM) + dir * EDIM + tid] = fminf(fmaxf(hnew, -CLIPV), CLIPV);
        }
        __syncthreads();  // B
    }
}

// ---------------------------------------------------------------------------
// R13 ctrl GRU scan: GRU-only, 128 WGs x 768 threads, same split-K scheme.
// Carry h clipped (ref); writes clipped h_t to hseq.
// ---------------------------------------------------------------------------
__global__ __launch_bounds__(768) void ctrl_scan_kernel(
    const float* __restrict__ cp,       // [T*B, 384]
    const float* __restrict__ Whh, const float* __restrict__ bhh,
    const float* __restrict__ ctrl_init,
    float* __restrict__ hseq)           // [T*B, 128]
{
    const int b    = blockIdx.x;
    const int tid  = threadIdx.x;
    const int lane = tid & 63;
    const int half = (tid >= 384) ? 1 : 0;
    const int row  = tid - half * 384;

    __shared__ float ph[768];
    __shared__ float h_lds[CDIM];

    const float4* __restrict__ wsrc = (const float4*)(Whh + (size_t)row * 128 + half * 64);
    float br = 0.f, bz = 0.f, bn = 0.f;
    if (tid < CDIM) {
        br = bhh[tid]; bz = bhh[CDIM + tid]; bn = bhh[2 * CDIM + tid];
        h_lds[tid] = ctrl_init[tid];
    }
    __syncthreads();

    for (int t = 0; t < TLEN; ++t) {
        const size_t row_g = (size_t)t * BATCH + b;
        float cxr = 0.f, cxz = 0.f, cxn = 0.f, hold = 0.f;
        if (tid < CDIM) {
            const float* __restrict__ cpr = cp + row_g * G3;
            cxr = cpr[tid]; cxz = cpr[CDIM + tid]; cxn = cpr[2 * CDIM + tid];
            hold = h_lds[tid];
        }
        const int hreg = __float_as_int(h_lds[half * 64 + lane]);
        float a0 = 0.f, a1 = 0.f, a2 = 0.f, a3 = 0.f;
        REP16(DOTH)
        ph[tid] = (a0 + a1) + (a2 + a3);
        __syncthreads();  // A
        if (tid < CDIM) {
            const float hr = ph[tid]            + ph[384 + tid]            + br;
            const float hz = ph[CDIM + tid]     + ph[384 + CDIM + tid]     + bz;
            const float hn = ph[2 * CDIM + tid] + ph[384 + 2 * CDIM + tid] + bn;
            const float rr = sigm(cxr + hr);
            const float zz = sigm(cxz + hz);
            const float nn = tanhf(cxn + rr * hn);
            float hnew = (1.f - zz) * nn + zz * hold;
            hnew = fminf(fmaxf(hnew, -CLIPV), CLIPV);         // carry clipped
            h_lds[tid] = hnew;
            hseq[row_g * CDIM + tid] = hnew;
        }
        __syncthreads();  // B
    }
}

// ---------------------------------------------------------------------------
// Concat [W_mu; W_lv] -> dst[128][128], [b_mu; b_lv] -> dst+16384. One block.
// ---------------------------------------------------------------------------
__global__ __launch_bounds__(256) void prep_mulv_kernel(
    const float* __restrict__ W_mu, const float* __restrict__ b_mu,
    const float* __restrict__ W_lv, const float* __restrict__ b_lv,
    float* __restrict__ dst)
{
    const int tid = threadIdx.x;
    for (int i = tid; i < UDIM * CDIM; i += 256) {
        dst[i] = W_mu[i];
        dst[UDIM * CDIM + i] = W_lv[i];
    }
    if (tid < UDIM) {
        dst[2 * UDIM * CDIM + tid] = b_mu[tid];
        dst[2 * UDIM * CDIM + UDIM + tid] = b_lv[tid];
    }
}

// ---------------------------------------------------------------------------
// u/gen: gen[row][0:64] = mu + exp(0.5 lv)*eps ; gen[row][64:68] = factors.
// ---------------------------------------------------------------------------
__global__ __launch_bounds__(128) void ugen_kernel(
    const float* __restrict__ mulv,     // [64000, 128] (mu | lv)
    const float* __restrict__ eps,      // [64000, 64]
    const float* __restrict__ factors,  // [64000, 4]
    float* __restrict__ gen)            // [64000, 68]
{
    const size_t row = blockIdx.x;
    const int tid = threadIdx.x;
    if (tid < UDIM) {
        const float mu = mulv[row * 128 + tid];
        const float lv = mulv[row * 128 + UDIM + tid];
        gen[row * (UDIM + FDIM) + tid] = mu + expf(0.5f * lv) * eps[row * UDIM + tid];
    } else if (tid < UDIM + FDIM) {
        gen[row * (UDIM + FDIM) + tid] = factors[row * FDIM + (tid - UDIM)];
    }
}

// ---------------------------------------------------------------------------
// AR1 calcium over t: 38400 independent (b,n) chains, coalesced per t.
// ---------------------------------------------------------------------------
__global__ __launch_bounds__(256) void ar1_kernel(
    const float* __restrict__ spike,    // [T*B, 300] raw gen@Wspk.T + b_spk
    const float* __restrict__ gain_p, const float* __restrict__ bias_p_p,
    const float* __restrict__ logtau_p,
    float* __restrict__ out)            // [T, B, 300]
{
    const int id = blockIdx.x * 256 + threadIdx.x;
    if (id >= BATCH * NDIM) return;
    const float gain  = gain_p[0];
    const float biasp = bias_p_p[0];
    const float decay = 1.0f - expf(-logtau_p[0]);
    float cal = 0.f;
#pragma unroll 4
    for (int t = 0; t < TLEN; ++t) {
        const float v  = spike[(size_t)t * (BATCH * NDIM) + id];
        const float sp = fmaxf(expf(v) - 1.0f, 0.0f);
        cal = cal * decay + gain * sp + biasp;
        out[(size_t)t * (BATCH * NDIM) + id] = cal;
    }
}

// ---------------------------------------------------------------------------
extern "C" void kernel_launch(void* const* d_in, const int* in_sizes, int n_in,
                              void* d_out, int out_size, void* d_ws, size_t ws_size,
                              hipStream_t stream) {
    const float* x         = (const float*)d_in[0];
    const float* factors   = (const float*)d_in[1];
    const float* eps       = (const float*)d_in[2];
    const float* enc_Wih_f = (const float*)d_in[3];
    const float* enc_Whh_f = (const float*)d_in[4];
    const float* enc_bih_f = (const float*)d_in[5];
    const float* enc_bhh_f = (const float*)d_in[6];
    const float* enc_Wih_b = (const float*)d_in[7];
    const float* enc_Whh_b = (const float*)d_in[8];
    const float* enc_bih_b = (const float*)d_in[9];
    const float* enc_bhh_b = (const float*)d_in[10];
    const float* enc_init  = (const float*)d_in[11];
    const float* ctrl_Wih  = (const float*)d_in[12];
    const float* ctrl_Whh  = (const float*)d_in[13];
    const float* ctrl_bih  = (const float*)d_in[14];
    const float* ctrl_bhh  = (const float*)d_in[15];
    const float* ctrl_init = (const float*)d_in[16];
    const float* W_mu      = (const float*)d_in[17];
    const float* b_mu      = (const float*)d_in[18];
    const float* W_lv      = (const float*)d_in[19];
    const float* b_lv      = (const float*)d_in[20];
    const float* W_spk     = (const float*)d_in[21];
    const float* b_spk     = (const float*)d_in[22];
    const float* gain      = (const float*)d_in[23];
    const float* bias_p    = (const float*)d_in[24];
    const float* logtau    = (const float*)d_in[25];
    float* out = (float*)d_out;
    float* ws  = (float*)d_ws;

    const size_t PROJ = (size_t)TLEN * BATCH * G3;   // 24,576,000 floats
    const size_t ROWS = (size_t)TLEN * BATCH;        // 64,000
    float* xpf   = ws;                     // [T*B,384]  -> later cp -> later spike
    float* xpb   = ws + PROJ;              // [T*B,384]  -> later hseq/mulv/gen
    float* g     = ws + 2 * PROJ;          // [T*B,256]  -> later wsmulv
    float* cp    = xpf;
    float* hseq  = xpb;                    // [T*B,128]
    float* mulv  = xpb + ROWS * 128;       // [T*B,128]
    float* gen   = xpb + 2 * ROWS * 128;   // [T*B,68]
    float* spike = xpf;                    // [T*B,300]
    float* wsmulv = g;                     // 16512 floats

    // 1) merged encoder projections
    gemm_fused_kernel<<<3000, 256, 0, stream>>>(
        x, NDIM, NDIM, 0,
        nullptr, 0, 0, 0,
        enc_Wih_f, enc_bih_f, xpf,
        enc_Wih_b, enc_bih_b, xpb,
        NDIM, G3, 2, 3, G3);
    // 2) bidirectional encoder scans -> g (clipped)
    enc_scan_kernel<<<256, 768, 0, stream>>>(xpf, enc_Whh_f, enc_bhh_f,
                                             enc_Whh_b, enc_bhh_b, enc_init, g);
    // 3) cp = g @ ctrl_Wih[:, :256].T + x @ ctrl_Wih[:, 256:].T + ctrl_bih
    gemm_fused_kernel<<<1500, 256, 0, stream>>>(
        g, 2 * EDIM, 2 * EDIM, 0,
        x, NDIM, NDIM, 2 * EDIM,
        ctrl_Wih, ctrl_bih, cp,
        nullptr, nullptr, nullptr,
        2 * EDIM + NDIM, G3, 1, 3, G3);
    // 4) concat W_mu/W_lv
    prep_mulv_kernel<<<1, 256, 0, stream>>>(W_mu, b_mu, W_lv, b_lv, wsmulv);
    // 5) controller GRU scan -> hseq (clipped)
    ctrl_scan_kernel<<<128, 768, 0, stream>>>(cp, ctrl_Whh, ctrl_bhh, ctrl_init, hseq);
    // 6) mulv = hseq @ [W_mu;W_lv].T + [b_mu;b_lv]
    gemm_fused_kernel<<<500, 256, 0, stream>>>(
        hseq, CDIM, CDIM, 0,
        nullptr, 0, 0, 0,
        wsmulv, wsmulv + 2 * UDIM * CDIM, mulv,
        nullptr, nullptr, nullptr,
        CDIM, CDIM, 1, 1, CDIM);
    // 7) gen = [mu + exp(0.5 lv)*eps | factors]
    ugen_kernel<<<(int)ROWS, 128, 0, stream>>>(mulv, eps, factors, gen);
    // 8) spike_raw = gen @ W_spk.T + b_spk
    gemm_fused_kernel<<<1500, 256, 0, stream>>>(
        gen, UDIM + FDIM, UDIM + FDIM, 0,
        nullptr, 0, 0, 0,
        W_spk, b_spk, spike,
        nullptr, nullptr, nullptr,
        UDIM + FDIM, NDIM, 1, 3, NDIM);
    // 9) calcium AR1 -> out
    ar1_kernel<<<(BATCH * NDIM + 255) / 256, 256, 0, stream>>>(
        spike, gain, bias_p, logtau, out);
}